// Round 8
// baseline (740.345 us; speedup 1.0000x reference)
//
#include <hip/hip_runtime.h>
#include <hip/hip_fp16.h>

#define NNODES    500000
#define SBSH      10            // super-bucket = dst >> 10
#define NSB       512           // super-bucket count (covers 524288 >= N)
#define SBN       1024          // nodes per super-bucket
#define CAP       17024         // staged region words (mean 16384, +5 sigma), mult of 16
#define PA_BLOCKS 250
#define NAGG      1954          // ceil(N/256)

// ---------------- passA: split edges into 512 super-buckets, 64B-chunked writes ----------------
__device__ __forceinline__ void insert_edge(unsigned b, unsigned w,
                                            unsigned int (*bin_data)[16],
                                            int* bin_cnt, int* bin_rdy,
                                            int* gcnt, unsigned int* staged) {
    int slot = atomicAdd(&bin_cnt[b], 1);
    if (slot < 16) {
        bin_data[b][slot] = w;
        __threadfence_block();
        int r = atomicAdd(&bin_rdy[b], 1);
        if (r == 15) {                         // completer of a full generation: flush 64B
            uint4 q0 = *(uint4*)&bin_data[b][0];
            uint4 q1 = *(uint4*)&bin_data[b][4];
            uint4 q2 = *(uint4*)&bin_data[b][8];
            uint4 q3 = *(uint4*)&bin_data[b][12];
            __threadfence_block();             // loads complete before slots reopen
            atomicExch(&bin_rdy[b], 0);
            atomicExch(&bin_cnt[b], 0);        // reopen bin (window was tiny)
            int pos = atomicAdd(&gcnt[b], 16); // 16-aligned positions -> aligned lines
            uint4* gp = (uint4*)(staged + (size_t)b * CAP + pos);
            gp[0] = q0; gp[1] = q1; gp[2] = q2; gp[3] = q3;
        }
    } else {
        // bin transiently full (flush in flight): direct write, no spinning -> no deadlock
        int pos = atomicAdd(&gcnt[b], 1);
        staged[(size_t)b * CAP + pos] = w;
    }
}

__global__ __launch_bounds__(256) void passA_kernel(const int* __restrict__ src,
                                                    const int* __restrict__ dst,
                                                    int* __restrict__ gcnt,
                                                    unsigned int* __restrict__ staged, int E) {
    __shared__ unsigned int bin_data[NSB][16];   // 32 KB
    __shared__ int bin_cnt[NSB];
    __shared__ int bin_rdy[NSB];
    const int t = threadIdx.x;
    for (int i = t; i < NSB; i += 256) { bin_cnt[i] = 0; bin_rdy[i] = 0; }
    __syncthreads();

    int C = (((E + PA_BLOCKS - 1) / PA_BLOCKS) + 3) & ~3;
    int lo = blockIdx.x * C;
    int hi = min(E, lo + C);
    if (lo < hi) {
        int rem = (hi - lo) & 3;
        for (int i = lo + 4 * t; i + 3 < hi; i += 4 * 256) {
            uint4 s4 = *(const uint4*)(src + i);
            uint4 d4 = *(const uint4*)(dst + i);
            insert_edge(d4.x >> SBSH, ((d4.x & (SBN - 1u)) << 19) | s4.x, bin_data, bin_cnt, bin_rdy, gcnt, staged);
            insert_edge(d4.y >> SBSH, ((d4.y & (SBN - 1u)) << 19) | s4.y, bin_data, bin_cnt, bin_rdy, gcnt, staged);
            insert_edge(d4.z >> SBSH, ((d4.z & (SBN - 1u)) << 19) | s4.z, bin_data, bin_cnt, bin_rdy, gcnt, staged);
            insert_edge(d4.w >> SBSH, ((d4.w & (SBN - 1u)) << 19) | s4.w, bin_data, bin_cnt, bin_rdy, gcnt, staged);
        }
        if (t < rem) {
            int j = hi - rem + t;
            unsigned d = (unsigned)dst[j], s = (unsigned)src[j];
            insert_edge(d >> SBSH, ((d & (SBN - 1u)) << 19) | s, bin_data, bin_cnt, bin_rdy, gcnt, staged);
        }
    }
    __syncthreads();
    // tail flush: residual (<16) entries per bin
    for (int b = t; b < NSB; b += 256) {
        int c = bin_cnt[b];
        if (c > 0) {
            int pos = atomicAdd(&gcnt[b], c);
            unsigned int* gp = staged + (size_t)b * CAP + pos;
            for (int k = 0; k < c; ++k) gp[k] = bin_data[b][k];
        }
    }
}

// ---------------- passB: per-super-bucket exact CSR + dinv + y1h ----------------
__global__ __launch_bounds__(256) void passB_kernel(const unsigned int* __restrict__ staged,
                                                    const int* __restrict__ gcnt,
                                                    unsigned int* __restrict__ eidx,
                                                    int* __restrict__ row_beg,
                                                    int* __restrict__ row_end,
                                                    float* __restrict__ dinv,
                                                    const float* __restrict__ x,
                                                    __half* __restrict__ y1h) {
    __shared__ int cnt[SBN];
    __shared__ int cur[SBN];
    __shared__ int tsum[256];
    const int t = threadIdx.x;
    const int g = blockIdx.x;
    const int len = gcnt[g];
    const int rb = g * CAP;

    for (int i = t; i < SBN; i += 256) cnt[i] = 0;
    __syncthreads();

    // histogram of dst-low-10
    int len4 = len & ~3;
    for (int k = 4 * t; k < len4; k += 1024) {
        uint4 p4 = *(const uint4*)(staged + rb + k);
        atomicAdd(&cnt[p4.x >> 19], 1);
        atomicAdd(&cnt[p4.y >> 19], 1);
        atomicAdd(&cnt[p4.z >> 19], 1);
        atomicAdd(&cnt[p4.w >> 19], 1);
    }
    for (int k = len4 + t; k < len; k += 256) atomicAdd(&cnt[staged[rb + k] >> 19], 1);
    __syncthreads();

    // block-wide exclusive scan of 1024 counts (4 per thread)
    int c0 = cnt[4 * t], c1 = cnt[4 * t + 1], c2 = cnt[4 * t + 2], c3 = cnt[4 * t + 3];
    int s = c0 + c1 + c2 + c3;
    tsum[t] = s;
    __syncthreads();
    for (int off = 1; off < 256; off <<= 1) {
        int v = (t >= off) ? tsum[t - off] : 0;
        __syncthreads();
        tsum[t] += v;
        __syncthreads();
    }
    int texcl = tsum[t] - s;
    cur[4 * t]     = texcl;
    cur[4 * t + 1] = texcl + c0;
    cur[4 * t + 2] = texcl + c0 + c1;
    cur[4 * t + 3] = texcl + c0 + c1 + c2;
    __syncthreads();

    // emit row_beg/row_end/dinv/y1h (before cur mutates)
    for (int l = t; l < SBN; l += 256) {
        int v = (g << SBSH) + l;
        if (v < NNODES) {
            int beg = rb + cur[l];
            row_beg[v] = beg;
            row_end[v] = beg + cnt[l];
            float di = rsqrtf((float)cnt[l] + 1.0f);
            dinv[v] = di;
            union { uint2 u; __half2 h[2]; } st;
            st.h[0] = __floats2half2_rn(di * x[3 * v + 0], di * x[3 * v + 1]);
            st.h[1] = __floats2half2_rn(di * x[3 * v + 2], 0.0f);
            *(uint2*)(y1h + 4 * (size_t)v) = st.u;
        }
    }
    __syncthreads();

    // scatter to exact CSR positions (writes within 68 KB L2-resident window)
    for (int k = 4 * t; k < len4; k += 1024) {
        uint4 p4 = *(const uint4*)(staged + rb + k);
        unsigned pp[4] = {p4.x, p4.y, p4.z, p4.w};
#pragma unroll
        for (int u = 0; u < 4; ++u) {
            int pos = atomicAdd(&cur[pp[u] >> 19], 1);
            eidx[rb + pos] = pp[u] & 0x7FFFFu;
        }
    }
    for (int k = len4 + t; k < len; k += 256) {
        unsigned p = staged[rb + k];
        int pos = atomicAdd(&cur[p >> 19], 1);
        eidx[rb + pos] = p & 0x7FFFFu;
    }
}

// ---------------- layer 1: node-centric register accumulation + fused transform ----------------
__global__ __launch_bounds__(256) void agg1t1_kernel(const unsigned int* __restrict__ eidx,
                                                     const int* __restrict__ row_beg,
                                                     const int* __restrict__ row_end,
                                                     const __half* __restrict__ y1h,
                                                     const float* __restrict__ dinv,
                                                     const float* __restrict__ W1,
                                                     const float* __restrict__ b1,
                                                     __half* __restrict__ y2h, int n) {
    int v = blockIdx.x * 256 + threadIdx.x;
    if (v >= n) return;
    int beg = row_beg[v], end = row_end[v];
    union { uint2 u2; __half2 h[2]; } sf;
    sf.u2 = *(const uint2*)(y1h + 4 * (size_t)v);
    float2 f01 = __half22float2(sf.h[0]);
    float2 f23 = __half22float2(sf.h[1]);
    float a0 = f01.x, a1 = f01.y, a2 = f23.x;
    int i = beg;
    for (; i + 3 < end; i += 4) {
        unsigned e0 = eidx[i], e1 = eidx[i + 1], e2 = eidx[i + 2], e3 = eidx[i + 3];
        uint2 w0 = *(const uint2*)(y1h + 4 * (size_t)e0);
        uint2 w1 = *(const uint2*)(y1h + 4 * (size_t)e1);
        uint2 w2 = *(const uint2*)(y1h + 4 * (size_t)e2);
        uint2 w3 = *(const uint2*)(y1h + 4 * (size_t)e3);
        uint2 ww[4] = {w0, w1, w2, w3};
#pragma unroll
        for (int u = 0; u < 4; ++u) {
            union { uint2 u2; __half2 h[2]; } g; g.u2 = ww[u];
            float2 p01 = __half22float2(g.h[0]);
            float2 p23 = __half22float2(g.h[1]);
            a0 += p01.x; a1 += p01.y; a2 += p23.x;
        }
    }
    for (; i < end; ++i) {
        unsigned e = eidx[i];
        union { uint2 u2; __half2 h[2]; } g;
        g.u2 = *(const uint2*)(y1h + 4 * (size_t)e);
        float2 p01 = __half22float2(g.h[0]);
        float2 p23 = __half22float2(g.h[1]);
        a0 += p01.x; a1 += p01.y; a2 += p23.x;
    }
    float di = dinv[v];
    a0 *= di; a1 *= di; a2 *= di;
    float hf[16];
#pragma unroll
    for (int j = 0; j < 16; ++j) {
        float h = b1[j] + a0 * W1[j] + a1 * W1[16 + j] + a2 * W1[32 + j];
        hf[j] = di * fmaxf(h, 0.0f);
    }
    union { uint4 u[2]; __half2 h[8]; } st;
#pragma unroll
    for (int q = 0; q < 8; ++q) st.h[q] = __floats2half2_rn(hf[2 * q], hf[2 * q + 1]);
    uint4* dp = (uint4*)(y2h + 16 * (size_t)v);
    dp[0] = st.u[0];
    dp[1] = st.u[1];
}

// ---------------- layer 2: node-centric register accumulation + fused transform ----------------
__device__ __forceinline__ void addh8(float* a, uint4 w) {
    union { uint4 u4; __half2 h[4]; } g; g.u4 = w;
#pragma unroll
    for (int q = 0; q < 4; ++q) {
        float2 f = __half22float2(g.h[q]);
        a[2 * q + 0] += f.x;
        a[2 * q + 1] += f.y;
    }
}

__global__ __launch_bounds__(256) void agg2t2_kernel(const unsigned int* __restrict__ eidx,
                                                     const int* __restrict__ row_beg,
                                                     const int* __restrict__ row_end,
                                                     const __half* __restrict__ y2h,
                                                     const float* __restrict__ dinv,
                                                     const float* __restrict__ W2,
                                                     const float* __restrict__ b2,
                                                     float* __restrict__ out, int n) {
    int v = blockIdx.x * 256 + threadIdx.x;
    if (v >= n) return;
    int beg = row_beg[v], end = row_end[v];
    float a[16];
    {
        const uint4* sp = (const uint4*)(y2h + 16 * (size_t)v);
        uint4 s0 = sp[0], s1 = sp[1];
        union { uint4 u4; __half2 h[4]; } g;
        g.u4 = s0;
#pragma unroll
        for (int q = 0; q < 4; ++q) {
            float2 f = __half22float2(g.h[q]);
            a[2 * q] = f.x; a[2 * q + 1] = f.y;
        }
        g.u4 = s1;
#pragma unroll
        for (int q = 0; q < 4; ++q) {
            float2 f = __half22float2(g.h[q]);
            a[8 + 2 * q] = f.x; a[8 + 2 * q + 1] = f.y;
        }
    }
    int i = beg;
    for (; i + 1 < end; i += 2) {
        unsigned e0 = eidx[i], e1 = eidx[i + 1];
        const uint4* p0 = (const uint4*)(y2h + 16 * (size_t)e0);
        const uint4* p1 = (const uint4*)(y2h + 16 * (size_t)e1);
        uint4 w0a = p0[0], w0b = p0[1], w1a = p1[0], w1b = p1[1];
        addh8(a, w0a); addh8(a + 8, w0b);
        addh8(a, w1a); addh8(a + 8, w1b);
    }
    if (i < end) {
        unsigned e = eidx[i];
        const uint4* p = (const uint4*)(y2h + 16 * (size_t)e);
        uint4 wa = p[0], wb = p[1];
        addh8(a, wa); addh8(a + 8, wb);
    }
    float di = dinv[v];
#pragma unroll
    for (int k = 0; k < 16; ++k) a[k] *= di;
    float z[10];
#pragma unroll
    for (int j = 0; j < 10; ++j) {
        float s = b2[j];
#pragma unroll
        for (int k = 0; k < 16; ++k) s += a[k] * W2[k * 10 + j];
        z[j] = s;
    }
    float m = z[0];
#pragma unroll
    for (int j = 1; j < 10; ++j) m = fmaxf(m, z[j]);
    float sum = 0.0f;
#pragma unroll
    for (int j = 0; j < 10; ++j) sum += expf(z[j] - m);
    float lse = logf(sum);
    float* ov = out + 10 * (size_t)v;
#pragma unroll
    for (int j = 0; j < 10; ++j) ov[j] = z[j] - m - lse;
}

extern "C" void kernel_launch(void* const* d_in, const int* in_sizes, int n_in,
                              void* d_out, int out_size, void* d_ws, size_t ws_size,
                              hipStream_t stream) {
    const float* x  = (const float*)d_in[0];
    const int*   ei = (const int*)d_in[1];
    const float* W1 = (const float*)d_in[2];
    const float* b1 = (const float*)d_in[3];
    const float* W2 = (const float*)d_in[4];
    const float* b2 = (const float*)d_in[5];
    float* out = (float*)d_out;

    const int E = in_sizes[1] / 2;            // 8,000,000
    const int* src = ei;
    const int* dst = ei + E;

    // workspace layout (words)
    int*          ws_i    = (int*)d_ws;
    int*          gcnt    = ws_i;                                   // 512
    int*          row_beg = ws_i + 512;                             // N
    int*          row_end = ws_i + 512 + 500000;                    // N
    float*        dinv    = (float*)(ws_i + 512 + 1000000);         // N
    __half*       y1h     = (__half*)(ws_i + 512 + 1500000);        // 4N halves (1M words)
    unsigned int* staged  = (unsigned int*)(ws_i + 512 + 2500000);  // 512*CAP = 8,716,288
    unsigned int* eidx    = staged + (size_t)NSB * CAP;             // 8,716,288
    __half*       y2h     = (__half*)staged;                        // overlay: staged dead after passB
    // total ~ 19.93M words = 79.7 MB

    hipMemsetAsync(gcnt, 0, NSB * sizeof(int), stream);

    passA_kernel<<<PA_BLOCKS, 256, 0, stream>>>(src, dst, gcnt, staged, E);
    passB_kernel<<<NSB, 256, 0, stream>>>(staged, gcnt, eidx, row_beg, row_end, dinv, x, y1h);
    agg1t1_kernel<<<NAGG, 256, 0, stream>>>(eidx, row_beg, row_end, y1h, dinv, W1, b1, y2h, NNODES);
    agg2t2_kernel<<<NAGG, 256, 0, stream>>>(eidx, row_beg, row_end, y2h, dinv, W2, b2, out, NNODES);
}

// Round 9
// 551.855 us; speedup vs baseline: 1.3416x; 1.3416x over previous
//
#include <hip/hip_runtime.h>
#include <hip/hip_fp16.h>

#define NNODES    500000
#define SBSH      10            // super-bucket = dst >> 10
#define NSB       512           // super-bucket count (covers 524288 >= N)
#define SBN       1024          // nodes per super-bucket
#define CAP       17024         // staged region words (mean 15625, +11 sigma), mult of 16
#define CHUNK     8192          // edges per scatter block
#define NAGG      1954          // ceil(N/256)

// ---------------- pass 1: coarse scatter into 512 super-buckets ----------------
// Per block: LDS histogram -> one global-cursor reservation per bucket -> clustered writes.
__global__ __launch_bounds__(256) void scatter_kernel(const int* __restrict__ src,
                                                      const int* __restrict__ dst,
                                                      int* __restrict__ gcursor,
                                                      unsigned int* __restrict__ staged, int E) {
    __shared__ int cnt[NSB];
    __shared__ int cur[NSB];
    const int t = threadIdx.x;
    for (int i = t; i < NSB; i += 256) cnt[i] = 0;
    __syncthreads();

    int lo = blockIdx.x * CHUNK;
    int hi = min(E, lo + CHUNK);
    int len4 = lo + ((hi - lo) & ~3);

    // phase 1: histogram of dst super-buckets (coalesced uint4 reads)
    for (int i = lo + 4 * t; i < len4; i += 1024) {
        uint4 d4 = *(const uint4*)(dst + i);
        atomicAdd(&cnt[d4.x >> SBSH], 1);
        atomicAdd(&cnt[d4.y >> SBSH], 1);
        atomicAdd(&cnt[d4.z >> SBSH], 1);
        atomicAdd(&cnt[d4.w >> SBSH], 1);
    }
    for (int i = len4 + t; i < hi; i += 256)
        atomicAdd(&cnt[((unsigned)dst[i]) >> SBSH], 1);
    __syncthreads();

    // reserve contiguous slots in each bucket region
    for (int b = t; b < NSB; b += 256) {
        int c = cnt[b];
        cur[b] = c ? atomicAdd(&gcursor[b], c) : 0;
    }
    __syncthreads();

    // phase 2: re-read and scatter into the block's contiguous slots
    for (int i = lo + 4 * t; i < len4; i += 1024) {
        uint4 d4 = *(const uint4*)(dst + i);
        uint4 s4 = *(const uint4*)(src + i);
        unsigned dd[4] = {d4.x, d4.y, d4.z, d4.w};
        unsigned ss[4] = {s4.x, s4.y, s4.z, s4.w};
#pragma unroll
        for (int u = 0; u < 4; ++u) {
            unsigned b = dd[u] >> SBSH;
            int pos = atomicAdd(&cur[b], 1);
            staged[(size_t)b * CAP + pos] = ((dd[u] & (SBN - 1u)) << 19) | ss[u];
        }
    }
    for (int i = len4 + t; i < hi; i += 256) {
        unsigned d = (unsigned)dst[i], s = (unsigned)src[i];
        unsigned b = d >> SBSH;
        int pos = atomicAdd(&cur[b], 1);
        staged[(size_t)b * CAP + pos] = ((d & (SBN - 1u)) << 19) | s;
    }
}

// ---------------- passB: per-super-bucket exact CSR + dinv + y1h ----------------
__global__ __launch_bounds__(256) void passB_kernel(const unsigned int* __restrict__ staged,
                                                    const int* __restrict__ gcnt,
                                                    unsigned int* __restrict__ eidx,
                                                    int* __restrict__ row_beg,
                                                    int* __restrict__ row_end,
                                                    float* __restrict__ dinv,
                                                    const float* __restrict__ x,
                                                    __half* __restrict__ y1h) {
    __shared__ int cnt[SBN];
    __shared__ int cur[SBN];
    __shared__ int tsum[256];
    const int t = threadIdx.x;
    const int g = blockIdx.x;
    const int len = gcnt[g];
    const int rb = g * CAP;

    for (int i = t; i < SBN; i += 256) cnt[i] = 0;
    __syncthreads();

    int len4 = len & ~3;
    for (int k = 4 * t; k < len4; k += 1024) {
        uint4 p4 = *(const uint4*)(staged + rb + k);
        atomicAdd(&cnt[p4.x >> 19], 1);
        atomicAdd(&cnt[p4.y >> 19], 1);
        atomicAdd(&cnt[p4.z >> 19], 1);
        atomicAdd(&cnt[p4.w >> 19], 1);
    }
    for (int k = len4 + t; k < len; k += 256) atomicAdd(&cnt[staged[rb + k] >> 19], 1);
    __syncthreads();

    int c0 = cnt[4 * t], c1 = cnt[4 * t + 1], c2 = cnt[4 * t + 2], c3 = cnt[4 * t + 3];
    int s = c0 + c1 + c2 + c3;
    tsum[t] = s;
    __syncthreads();
    for (int off = 1; off < 256; off <<= 1) {
        int v = (t >= off) ? tsum[t - off] : 0;
        __syncthreads();
        tsum[t] += v;
        __syncthreads();
    }
    int texcl = tsum[t] - s;
    cur[4 * t]     = texcl;
    cur[4 * t + 1] = texcl + c0;
    cur[4 * t + 2] = texcl + c0 + c1;
    cur[4 * t + 3] = texcl + c0 + c1 + c2;
    __syncthreads();

    for (int l = t; l < SBN; l += 256) {
        int v = (g << SBSH) + l;
        if (v < NNODES) {
            int beg = rb + cur[l];
            row_beg[v] = beg;
            row_end[v] = beg + cnt[l];
            float di = rsqrtf((float)cnt[l] + 1.0f);
            dinv[v] = di;
            union { uint2 u; __half2 h[2]; } st;
            st.h[0] = __floats2half2_rn(di * x[3 * v + 0], di * x[3 * v + 1]);
            st.h[1] = __floats2half2_rn(di * x[3 * v + 2], 0.0f);
            *(uint2*)(y1h + 4 * (size_t)v) = st.u;
        }
    }
    __syncthreads();

    for (int k = 4 * t; k < len4; k += 1024) {
        uint4 p4 = *(const uint4*)(staged + rb + k);
        unsigned pp[4] = {p4.x, p4.y, p4.z, p4.w};
#pragma unroll
        for (int u = 0; u < 4; ++u) {
            int pos = atomicAdd(&cur[pp[u] >> 19], 1);
            eidx[rb + pos] = pp[u] & 0x7FFFFu;
        }
    }
    for (int k = len4 + t; k < len; k += 256) {
        unsigned p = staged[rb + k];
        int pos = atomicAdd(&cur[p >> 19], 1);
        eidx[rb + pos] = p & 0x7FFFFu;
    }
}

// ---------------- layer 1: node-centric register accumulation + fused transform ----------------
__global__ __launch_bounds__(256) void agg1t1_kernel(const unsigned int* __restrict__ eidx,
                                                     const int* __restrict__ row_beg,
                                                     const int* __restrict__ row_end,
                                                     const __half* __restrict__ y1h,
                                                     const float* __restrict__ dinv,
                                                     const float* __restrict__ W1,
                                                     const float* __restrict__ b1,
                                                     __half* __restrict__ y2h, int n) {
    int v = blockIdx.x * 256 + threadIdx.x;
    if (v >= n) return;
    int beg = row_beg[v], end = row_end[v];
    union { uint2 u2; __half2 h[2]; } sf;
    sf.u2 = *(const uint2*)(y1h + 4 * (size_t)v);
    float2 f01 = __half22float2(sf.h[0]);
    float2 f23 = __half22float2(sf.h[1]);
    float a0 = f01.x, a1 = f01.y, a2 = f23.x;
    int i = beg;
    for (; i + 3 < end; i += 4) {
        unsigned e0 = eidx[i], e1 = eidx[i + 1], e2 = eidx[i + 2], e3 = eidx[i + 3];
        uint2 w0 = *(const uint2*)(y1h + 4 * (size_t)e0);
        uint2 w1 = *(const uint2*)(y1h + 4 * (size_t)e1);
        uint2 w2 = *(const uint2*)(y1h + 4 * (size_t)e2);
        uint2 w3 = *(const uint2*)(y1h + 4 * (size_t)e3);
        uint2 ww[4] = {w0, w1, w2, w3};
#pragma unroll
        for (int u = 0; u < 4; ++u) {
            union { uint2 u2; __half2 h[2]; } g; g.u2 = ww[u];
            float2 p01 = __half22float2(g.h[0]);
            float2 p23 = __half22float2(g.h[1]);
            a0 += p01.x; a1 += p01.y; a2 += p23.x;
        }
    }
    for (; i < end; ++i) {
        unsigned e = eidx[i];
        union { uint2 u2; __half2 h[2]; } g;
        g.u2 = *(const uint2*)(y1h + 4 * (size_t)e);
        float2 p01 = __half22float2(g.h[0]);
        float2 p23 = __half22float2(g.h[1]);
        a0 += p01.x; a1 += p01.y; a2 += p23.x;
    }
    float di = dinv[v];
    a0 *= di; a1 *= di; a2 *= di;
    float hf[16];
#pragma unroll
    for (int j = 0; j < 16; ++j) {
        float h = b1[j] + a0 * W1[j] + a1 * W1[16 + j] + a2 * W1[32 + j];
        hf[j] = di * fmaxf(h, 0.0f);
    }
    union { uint4 u[2]; __half2 h[8]; } st;
#pragma unroll
    for (int q = 0; q < 8; ++q) st.h[q] = __floats2half2_rn(hf[2 * q], hf[2 * q + 1]);
    uint4* dp = (uint4*)(y2h + 16 * (size_t)v);
    dp[0] = st.u[0];
    dp[1] = st.u[1];
}

// ---------------- layer 2: node-centric register accumulation + fused transform ----------------
__device__ __forceinline__ void addh8(float* a, uint4 w) {
    union { uint4 u4; __half2 h[4]; } g; g.u4 = w;
#pragma unroll
    for (int q = 0; q < 4; ++q) {
        float2 f = __half22float2(g.h[q]);
        a[2 * q + 0] += f.x;
        a[2 * q + 1] += f.y;
    }
}

__global__ __launch_bounds__(256) void agg2t2_kernel(const unsigned int* __restrict__ eidx,
                                                     const int* __restrict__ row_beg,
                                                     const int* __restrict__ row_end,
                                                     const __half* __restrict__ y2h,
                                                     const float* __restrict__ dinv,
                                                     const float* __restrict__ W2,
                                                     const float* __restrict__ b2,
                                                     float* __restrict__ out, int n) {
    int v = blockIdx.x * 256 + threadIdx.x;
    if (v >= n) return;
    int beg = row_beg[v], end = row_end[v];
    float a[16];
    {
        const uint4* sp = (const uint4*)(y2h + 16 * (size_t)v);
        uint4 s0 = sp[0], s1 = sp[1];
        union { uint4 u4; __half2 h[4]; } g;
        g.u4 = s0;
#pragma unroll
        for (int q = 0; q < 4; ++q) {
            float2 f = __half22float2(g.h[q]);
            a[2 * q] = f.x; a[2 * q + 1] = f.y;
        }
        g.u4 = s1;
#pragma unroll
        for (int q = 0; q < 4; ++q) {
            float2 f = __half22float2(g.h[q]);
            a[8 + 2 * q] = f.x; a[8 + 2 * q + 1] = f.y;
        }
    }
    int i = beg;
    for (; i + 1 < end; i += 2) {
        unsigned e0 = eidx[i], e1 = eidx[i + 1];
        const uint4* p0 = (const uint4*)(y2h + 16 * (size_t)e0);
        const uint4* p1 = (const uint4*)(y2h + 16 * (size_t)e1);
        uint4 w0a = p0[0], w0b = p0[1], w1a = p1[0], w1b = p1[1];
        addh8(a, w0a); addh8(a + 8, w0b);
        addh8(a, w1a); addh8(a + 8, w1b);
    }
    if (i < end) {
        unsigned e = eidx[i];
        const uint4* p = (const uint4*)(y2h + 16 * (size_t)e);
        uint4 wa = p[0], wb = p[1];
        addh8(a, wa); addh8(a + 8, wb);
    }
    float di = dinv[v];
#pragma unroll
    for (int k = 0; k < 16; ++k) a[k] *= di;
    float z[10];
#pragma unroll
    for (int j = 0; j < 10; ++j) {
        float s = b2[j];
#pragma unroll
        for (int k = 0; k < 16; ++k) s += a[k] * W2[k * 10 + j];
        z[j] = s;
    }
    float m = z[0];
#pragma unroll
    for (int j = 1; j < 10; ++j) m = fmaxf(m, z[j]);
    float sum = 0.0f;
#pragma unroll
    for (int j = 0; j < 10; ++j) sum += expf(z[j] - m);
    float lse = logf(sum);
    float* ov = out + 10 * (size_t)v;
#pragma unroll
    for (int j = 0; j < 10; ++j) ov[j] = z[j] - m - lse;
}

extern "C" void kernel_launch(void* const* d_in, const int* in_sizes, int n_in,
                              void* d_out, int out_size, void* d_ws, size_t ws_size,
                              hipStream_t stream) {
    const float* x  = (const float*)d_in[0];
    const int*   ei = (const int*)d_in[1];
    const float* W1 = (const float*)d_in[2];
    const float* b1 = (const float*)d_in[3];
    const float* W2 = (const float*)d_in[4];
    const float* b2 = (const float*)d_in[5];
    float* out = (float*)d_out;

    const int E = in_sizes[1] / 2;            // 8,000,000
    const int* src = ei;
    const int* dst = ei + E;

    // workspace layout (words)
    int*          ws_i    = (int*)d_ws;
    int*          gcursor = ws_i;                                   // 512
    int*          row_beg = ws_i + 512;                             // N
    int*          row_end = ws_i + 512 + 500000;                    // N
    float*        dinv    = (float*)(ws_i + 512 + 1000000);         // N
    __half*       y1h     = (__half*)(ws_i + 512 + 1500000);        // 4N halves (1M words)
    unsigned int* staged  = (unsigned int*)(ws_i + 512 + 2500000);  // 512*CAP = 8,716,288
    unsigned int* eidx    = staged + (size_t)NSB * CAP;             // 8,716,288
    __half*       y2h     = (__half*)staged;                        // overlay: staged dead after passB
    // total ~ 19.93M words = 79.7 MB

    hipMemsetAsync(gcursor, 0, NSB * sizeof(int), stream);

    int nblk = (E + CHUNK - 1) / CHUNK;       // 977
    scatter_kernel<<<nblk, 256, 0, stream>>>(src, dst, gcursor, staged, E);
    passB_kernel<<<NSB, 256, 0, stream>>>(staged, gcursor, eidx, row_beg, row_end, dinv, x, y1h);
    agg1t1_kernel<<<NAGG, 256, 0, stream>>>(eidx, row_beg, row_end, y1h, dinv, W1, b1, y2h, NNODES);
    agg2t2_kernel<<<NAGG, 256, 0, stream>>>(eidx, row_beg, row_end, y2h, dinv, W2, b2, out, NNODES);
}

// Round 10
// 524.114 us; speedup vs baseline: 1.4126x; 1.0529x over previous
//
#include <hip/hip_runtime.h>
#include <hip/hip_fp16.h>

#define NNODES    500000
#define SBSH      10            // super-bucket = dst >> 10
#define NSB       512           // super-bucket count (covers 524288 >= N)
#define SBN       1024          // nodes per super-bucket
#define CAP       17024         // staged region words (mean 15625, +11 sigma), mult of 16
#define CHUNK     8192          // edges per scatter block
#define NAGG      1954          // ceil(N/256)
#define NBIN      8192          // passB bins: dst_low10 * 8 + src_high3

// bin key: group rows by dst, order within row by src-chunk (2 MB y2h windows)
#define BIN(p) ((int)(((p) >> 19) * 8u + (((p) & 0x7FFFFu) >> 16)))

// ---------------- pass 1: coarse scatter into 512 super-buckets ----------------
__global__ __launch_bounds__(256) void scatter_kernel(const int* __restrict__ src,
                                                      const int* __restrict__ dst,
                                                      int* __restrict__ gcursor,
                                                      unsigned int* __restrict__ staged, int E) {
    __shared__ int cnt[NSB];
    __shared__ int cur[NSB];
    const int t = threadIdx.x;
    for (int i = t; i < NSB; i += 256) cnt[i] = 0;
    __syncthreads();

    int lo = blockIdx.x * CHUNK;
    int hi = min(E, lo + CHUNK);
    int len4 = lo + ((hi - lo) & ~3);

    for (int i = lo + 4 * t; i < len4; i += 1024) {
        uint4 d4 = *(const uint4*)(dst + i);
        atomicAdd(&cnt[d4.x >> SBSH], 1);
        atomicAdd(&cnt[d4.y >> SBSH], 1);
        atomicAdd(&cnt[d4.z >> SBSH], 1);
        atomicAdd(&cnt[d4.w >> SBSH], 1);
    }
    for (int i = len4 + t; i < hi; i += 256)
        atomicAdd(&cnt[((unsigned)dst[i]) >> SBSH], 1);
    __syncthreads();

    for (int b = t; b < NSB; b += 256) {
        int c = cnt[b];
        cur[b] = c ? atomicAdd(&gcursor[b], c) : 0;
    }
    __syncthreads();

    for (int i = lo + 4 * t; i < len4; i += 1024) {
        uint4 d4 = *(const uint4*)(dst + i);
        uint4 s4 = *(const uint4*)(src + i);
        unsigned dd[4] = {d4.x, d4.y, d4.z, d4.w};
        unsigned ss[4] = {s4.x, s4.y, s4.z, s4.w};
#pragma unroll
        for (int u = 0; u < 4; ++u) {
            unsigned b = dd[u] >> SBSH;
            int pos = atomicAdd(&cur[b], 1);
            staged[(size_t)b * CAP + pos] = ((dd[u] & (SBN - 1u)) << 19) | ss[u];
        }
    }
    for (int i = len4 + t; i < hi; i += 256) {
        unsigned d = (unsigned)dst[i], s = (unsigned)src[i];
        unsigned b = d >> SBSH;
        int pos = atomicAdd(&cur[b], 1);
        staged[(size_t)b * CAP + pos] = ((d & (SBN - 1u)) << 19) | s;
    }
}

// ---------------- passB: per-super-bucket CSR, rows src-chunk-ordered ----------------
__global__ __launch_bounds__(256) void passB_kernel(const unsigned int* __restrict__ staged,
                                                    const int* __restrict__ gcnt,
                                                    unsigned int* __restrict__ eidx,
                                                    int* __restrict__ row_beg,
                                                    int* __restrict__ row_end,
                                                    float* __restrict__ dinv,
                                                    const float* __restrict__ x,
                                                    __half* __restrict__ y1h) {
    __shared__ int bins[NBIN];                // 32 KB
    __shared__ int tsum[256];
    const int t = threadIdx.x;
    const int g = blockIdx.x;
    const int len = gcnt[g];
    const int rb = g * CAP;

    for (int i = t; i < NBIN; i += 256) bins[i] = 0;
    __syncthreads();

    // histogram over 8192 (dst_low, src_chunk) bins
    int len4 = len & ~3;
    for (int k = 4 * t; k < len4; k += 1024) {
        uint4 p4 = *(const uint4*)(staged + rb + k);
        atomicAdd(&bins[BIN(p4.x)], 1);
        atomicAdd(&bins[BIN(p4.y)], 1);
        atomicAdd(&bins[BIN(p4.z)], 1);
        atomicAdd(&bins[BIN(p4.w)], 1);
    }
    for (int k = len4 + t; k < len; k += 256) atomicAdd(&bins[BIN(staged[rb + k])], 1);
    __syncthreads();

    // in-place exclusive scan of 8192 bins (32 per thread + block scan)
    int base_ = 32 * t;
    int run = 0;
#pragma unroll
    for (int j = 0; j < 32; ++j) {
        int c = bins[base_ + j];
        bins[base_ + j] = run;
        run += c;
    }
    tsum[t] = run;
    __syncthreads();
    for (int off = 1; off < 256; off <<= 1) {
        int v = (t >= off) ? tsum[t - off] : 0;
        __syncthreads();
        tsum[t] += v;
        __syncthreads();
    }
    int off0 = tsum[t] - run;
#pragma unroll
    for (int j = 0; j < 32; ++j) bins[base_ + j] += off0;
    __syncthreads();

    // emit row data (before bins mutate as cursors)
    for (int l = t; l < SBN; l += 256) {
        int v = (g << SBSH) + l;
        if (v < NNODES) {
            int b0 = bins[8 * l];
            int b1 = (l == SBN - 1) ? len : bins[8 * l + 8];
            row_beg[v] = rb + b0;
            row_end[v] = rb + b1;
            float di = rsqrtf((float)(b1 - b0) + 1.0f);
            dinv[v] = di;
            union { uint2 u; __half2 h[2]; } st;
            st.h[0] = __floats2half2_rn(di * x[3 * v + 0], di * x[3 * v + 1]);
            st.h[1] = __floats2half2_rn(di * x[3 * v + 2], 0.0f);
            *(uint2*)(y1h + 4 * (size_t)v) = st.u;
        }
    }
    __syncthreads();

    // scatter to exact positions (writes stay in the 68 KB L2-resident window)
    for (int k = 4 * t; k < len4; k += 1024) {
        uint4 p4 = *(const uint4*)(staged + rb + k);
        unsigned pp[4] = {p4.x, p4.y, p4.z, p4.w};
#pragma unroll
        for (int u = 0; u < 4; ++u) {
            int pos = atomicAdd(&bins[BIN(pp[u])], 1);
            eidx[rb + pos] = pp[u] & 0x7FFFFu;
        }
    }
    for (int k = len4 + t; k < len; k += 256) {
        unsigned p = staged[rb + k];
        int pos = atomicAdd(&bins[BIN(p)], 1);
        eidx[rb + pos] = p & 0x7FFFFu;
    }
}

// ---------------- layer 1: node-centric register accumulation + fused transform ----------------
__global__ __launch_bounds__(256) void agg1t1_kernel(const unsigned int* __restrict__ eidx,
                                                     const int* __restrict__ row_beg,
                                                     const int* __restrict__ row_end,
                                                     const __half* __restrict__ y1h,
                                                     const float* __restrict__ dinv,
                                                     const float* __restrict__ W1,
                                                     const float* __restrict__ b1,
                                                     __half* __restrict__ y2h, int n) {
    int v = blockIdx.x * 256 + threadIdx.x;
    if (v >= n) return;
    int beg = row_beg[v], end = row_end[v];
    union { uint2 u2; __half2 h[2]; } sf;
    sf.u2 = *(const uint2*)(y1h + 4 * (size_t)v);
    float2 f01 = __half22float2(sf.h[0]);
    float2 f23 = __half22float2(sf.h[1]);
    float a0 = f01.x, a1 = f01.y, a2 = f23.x;
    int i = beg;
    for (; i + 3 < end; i += 4) {
        unsigned e0 = eidx[i], e1 = eidx[i + 1], e2 = eidx[i + 2], e3 = eidx[i + 3];
        uint2 w0 = *(const uint2*)(y1h + 4 * (size_t)e0);
        uint2 w1 = *(const uint2*)(y1h + 4 * (size_t)e1);
        uint2 w2 = *(const uint2*)(y1h + 4 * (size_t)e2);
        uint2 w3 = *(const uint2*)(y1h + 4 * (size_t)e3);
        uint2 ww[4] = {w0, w1, w2, w3};
#pragma unroll
        for (int u = 0; u < 4; ++u) {
            union { uint2 u2; __half2 h[2]; } g; g.u2 = ww[u];
            float2 p01 = __half22float2(g.h[0]);
            float2 p23 = __half22float2(g.h[1]);
            a0 += p01.x; a1 += p01.y; a2 += p23.x;
        }
    }
    for (; i < end; ++i) {
        unsigned e = eidx[i];
        union { uint2 u2; __half2 h[2]; } g;
        g.u2 = *(const uint2*)(y1h + 4 * (size_t)e);
        float2 p01 = __half22float2(g.h[0]);
        float2 p23 = __half22float2(g.h[1]);
        a0 += p01.x; a1 += p01.y; a2 += p23.x;
    }
    float di = dinv[v];
    a0 *= di; a1 *= di; a2 *= di;
    float hf[16];
#pragma unroll
    for (int j = 0; j < 16; ++j) {
        float h = b1[j] + a0 * W1[j] + a1 * W1[16 + j] + a2 * W1[32 + j];
        hf[j] = di * fmaxf(h, 0.0f);
    }
    union { uint4 u[2]; __half2 h[8]; } st;
#pragma unroll
    for (int q = 0; q < 8; ++q) st.h[q] = __floats2half2_rn(hf[2 * q], hf[2 * q + 1]);
    uint4* dp = (uint4*)(y2h + 16 * (size_t)v);
    dp[0] = st.u[0];
    dp[1] = st.u[1];
}

// ---------------- layer 2: node-centric register accumulation + fused transform ----------------
__device__ __forceinline__ void addh8(float* a, uint4 w) {
    union { uint4 u4; __half2 h[4]; } g; g.u4 = w;
#pragma unroll
    for (int q = 0; q < 4; ++q) {
        float2 f = __half22float2(g.h[q]);
        a[2 * q + 0] += f.x;
        a[2 * q + 1] += f.y;
    }
}

__global__ __launch_bounds__(256) void agg2t2_kernel(const unsigned int* __restrict__ eidx,
                                                     const int* __restrict__ row_beg,
                                                     const int* __restrict__ row_end,
                                                     const __half* __restrict__ y2h,
                                                     const float* __restrict__ dinv,
                                                     const float* __restrict__ W2,
                                                     const float* __restrict__ b2,
                                                     float* __restrict__ out, int n) {
    int v = blockIdx.x * 256 + threadIdx.x;
    if (v >= n) return;
    int beg = row_beg[v], end = row_end[v];
    float a[16];
    {
        const uint4* sp = (const uint4*)(y2h + 16 * (size_t)v);
        uint4 s0 = sp[0], s1 = sp[1];
        union { uint4 u4; __half2 h[4]; } g;
        g.u4 = s0;
#pragma unroll
        for (int q = 0; q < 4; ++q) {
            float2 f = __half22float2(g.h[q]);
            a[2 * q] = f.x; a[2 * q + 1] = f.y;
        }
        g.u4 = s1;
#pragma unroll
        for (int q = 0; q < 4; ++q) {
            float2 f = __half22float2(g.h[q]);
            a[8 + 2 * q] = f.x; a[8 + 2 * q + 1] = f.y;
        }
    }
    int i = beg;
    for (; i + 3 < end; i += 4) {
        unsigned e0 = eidx[i], e1 = eidx[i + 1], e2 = eidx[i + 2], e3 = eidx[i + 3];
        const uint4* p0 = (const uint4*)(y2h + 16 * (size_t)e0);
        const uint4* p1 = (const uint4*)(y2h + 16 * (size_t)e1);
        const uint4* p2 = (const uint4*)(y2h + 16 * (size_t)e2);
        const uint4* p3 = (const uint4*)(y2h + 16 * (size_t)e3);
        uint4 w0a = p0[0], w0b = p0[1];
        uint4 w1a = p1[0], w1b = p1[1];
        uint4 w2a = p2[0], w2b = p2[1];
        uint4 w3a = p3[0], w3b = p3[1];
        addh8(a, w0a); addh8(a + 8, w0b);
        addh8(a, w1a); addh8(a + 8, w1b);
        addh8(a, w2a); addh8(a + 8, w2b);
        addh8(a, w3a); addh8(a + 8, w3b);
    }
    for (; i < end; ++i) {
        unsigned e = eidx[i];
        const uint4* p = (const uint4*)(y2h + 16 * (size_t)e);
        uint4 wa = p[0], wb = p[1];
        addh8(a, wa); addh8(a + 8, wb);
    }
    float di = dinv[v];
#pragma unroll
    for (int k = 0; k < 16; ++k) a[k] *= di;
    float z[10];
#pragma unroll
    for (int j = 0; j < 10; ++j) {
        float s = b2[j];
#pragma unroll
        for (int k = 0; k < 16; ++k) s += a[k] * W2[k * 10 + j];
        z[j] = s;
    }
    float m = z[0];
#pragma unroll
    for (int j = 1; j < 10; ++j) m = fmaxf(m, z[j]);
    float sum = 0.0f;
#pragma unroll
    for (int j = 0; j < 10; ++j) sum += expf(z[j] - m);
    float lse = logf(sum);
    float* ov = out + 10 * (size_t)v;
#pragma unroll
    for (int j = 0; j < 10; ++j) ov[j] = z[j] - m - lse;
}

extern "C" void kernel_launch(void* const* d_in, const int* in_sizes, int n_in,
                              void* d_out, int out_size, void* d_ws, size_t ws_size,
                              hipStream_t stream) {
    const float* x  = (const float*)d_in[0];
    const int*   ei = (const int*)d_in[1];
    const float* W1 = (const float*)d_in[2];
    const float* b1 = (const float*)d_in[3];
    const float* W2 = (const float*)d_in[4];
    const float* b2 = (const float*)d_in[5];
    float* out = (float*)d_out;

    const int E = in_sizes[1] / 2;            // 8,000,000
    const int* src = ei;
    const int* dst = ei + E;

    // workspace layout (words)
    int*          ws_i    = (int*)d_ws;
    int*          gcursor = ws_i;                                   // 512
    int*          row_beg = ws_i + 512;                             // N
    int*          row_end = ws_i + 512 + 500000;                    // N
    float*        dinv    = (float*)(ws_i + 512 + 1000000);         // N
    __half*       y1h     = (__half*)(ws_i + 512 + 1500000);        // 4N halves (1M words)
    unsigned int* staged  = (unsigned int*)(ws_i + 512 + 2500000);  // 512*CAP = 8,716,288
    unsigned int* eidx    = staged + (size_t)NSB * CAP;             // 8,716,288
    __half*       y2h     = (__half*)staged;                        // overlay: staged dead after passB
    // total ~ 19.93M words = 79.7 MB

    hipMemsetAsync(gcursor, 0, NSB * sizeof(int), stream);

    int nblk = (E + CHUNK - 1) / CHUNK;       // 977
    scatter_kernel<<<nblk, 256, 0, stream>>>(src, dst, gcursor, staged, E);
    passB_kernel<<<NSB, 256, 0, stream>>>(staged, gcursor, eidx, row_beg, row_end, dinv, x, y1h);
    agg1t1_kernel<<<NAGG, 256, 0, stream>>>(eidx, row_beg, row_end, y1h, dinv, W1, b1, y2h, NNODES);
    agg2t2_kernel<<<NAGG, 256, 0, stream>>>(eidx, row_beg, row_end, y2h, dinv, W2, b2, out, NNODES);
}